// Round 3
// baseline (921.134 us; speedup 1.0000x reference)
//
#include <hip/hip_runtime.h>

// GraphSAGE-pool forward, fp32.
// Pipeline: CSR-build(dst) -> m1=relu(x@Wp1+bp1) -> agg1=segmax -> h1=l2n(relu(x@Ws1+agg1@Wn1+b1))
//        -> m2=relu(h1@Wp2+bp2) -> agg2=segmax -> [h2=l2n(h1@Ws2+agg2@Wn2+b2); ps/pd=h2@Wpred halves] (fused)
//        -> score[e]=ps[src]+pd[dst]+bpred

constexpr int D = 128;

// ---------------- CSR build ----------------
__global__ void k_count(const int* __restrict__ dst, int* __restrict__ counts, int E) {
    int e = blockIdx.x * blockDim.x + threadIdx.x;
    if (e < E) atomicAdd(&counts[dst[e]], 1);
}

__global__ void k_scan1(const int* __restrict__ counts, int* __restrict__ offs,
                        int* __restrict__ bsum, int n) {
    __shared__ int sh[1024];
    int tid = threadIdx.x;
    int i = blockIdx.x * 1024 + tid;
    int c = (i < n) ? counts[i] : 0;
    sh[tid] = c;
    __syncthreads();
    for (int off = 1; off < 1024; off <<= 1) {
        int v = (tid >= off) ? sh[tid - off] : 0;
        __syncthreads();
        sh[tid] += v;
        __syncthreads();
    }
    if (i < n) offs[i] = sh[tid] - c;           // block-local exclusive
    if (tid == 1023) bsum[blockIdx.x] = sh[1023];
}

__global__ void k_scan2(int* __restrict__ bsum, int nb) {
    __shared__ int sh[1024];
    int tid = threadIdx.x;
    int c = (tid < nb) ? bsum[tid] : 0;
    sh[tid] = c;
    __syncthreads();
    for (int off = 1; off < 1024; off <<= 1) {
        int v = (tid >= off) ? sh[tid - off] : 0;
        __syncthreads();
        sh[tid] += v;
        __syncthreads();
    }
    if (tid < nb) bsum[tid] = sh[tid] - c;      // exclusive block offsets
}

__global__ void k_scan3(int* __restrict__ offs, const int* __restrict__ bsum, int n) {
    int i = blockIdx.x * 1024 + threadIdx.x;
    if (i < n) offs[i] += bsum[blockIdx.x];
}

__global__ void k_scatter(const int* __restrict__ src, const int* __restrict__ dst,
                          const int* __restrict__ offs, int* __restrict__ cursor,
                          int* __restrict__ csr, int E) {
    int e = blockIdx.x * blockDim.x + threadIdx.x;
    if (e < E) {
        int d = dst[e];
        int pos = offs[d] + atomicAdd(&cursor[d], 1);
        csr[pos] = src[e];
    }
}

// ---------------- GEMM: C = act(A@W1 [+ G@W2] + bias), optional row-l2norm ----------------
// 128x128 output tile / 256 threads / 8x8 microtile (cols tc*4.. and 64+tc*4..).
// K staged in 64-wide chunks: sA[128][65] (33.3KB) + sW[64][128] (32KB) -> 2 blocks/CU.
// Reg-staged prefetch: chunk c's global loads issue BEFORE mma(c-1) (T14 issue-early).
// PRED: fuse ps/pd = C @ Wpred-halves into epilogue and skip the C store entirely.
template<bool DUAL, bool RELU, bool L2N, bool PRED>
__global__ __launch_bounds__(256, 2) void k_gemm(
    const float* __restrict__ A, const float* __restrict__ G,
    const float* __restrict__ W1, const float* __restrict__ W2,
    const float* __restrict__ bias, float* __restrict__ C,
    const float* __restrict__ Wpred, float* __restrict__ ps, float* __restrict__ pd,
    int nrows)
{
    __shared__ float sA[128 * 65];   // stride 65 (odd): per-k column reads conflict-free
    __shared__ float sW[64 * 128];
    const int tid  = threadIdx.x;
    const int tc   = tid & 15;       // lane bits 0-3
    const int tr   = tid >> 4;
    const int row0 = blockIdx.x * 128;

    float acc[8][8];
    #pragma unroll
    for (int i = 0; i < 8; ++i)
        #pragma unroll
        for (int j = 0; j < 8; ++j) acc[i][j] = 0.f;

    float4 pa[8], pw[8];             // staging registers (64 VGPR)

    auto load_regs = [&](const float* __restrict__ Asrc, const float* __restrict__ Wsrc, int k0) {
        #pragma unroll
        for (int it = 0; it < 8; ++it) {
            int idx = tid + it * 256;            // 0..2047
            int r = idx >> 4, cg = idx & 15;     // A: 128 rows x 16 float4
            pa[it] = make_float4(0.f, 0.f, 0.f, 0.f);
            if (row0 + r < nrows)
                pa[it] = *(const float4*)(Asrc + (size_t)(row0 + r) * D + k0 + cg * 4);
            pw[it] = *(const float4*)(Wsrc + (size_t)k0 * D + idx * 4);   // rows k0..k0+63 linear
        }
    };
    auto store_lds = [&]() {
        #pragma unroll
        for (int it = 0; it < 8; ++it) {
            int idx = tid + it * 256;
            int r = idx >> 4, cg = idx & 15;
            float* p = &sA[r * 65 + cg * 4];     // scalar stores (padded stride)
            p[0] = pa[it].x; p[1] = pa[it].y; p[2] = pa[it].z; p[3] = pa[it].w;
            *(float4*)&sW[idx * 4] = pw[it];
        }
    };
    auto mma = [&]() {
        #pragma unroll 4
        for (int kk = 0; kk < 64; ++kk) {
            float w[8];
            *(float4*)&w[0] = *(const float4*)&sW[kk * D + tc * 4];
            *(float4*)&w[4] = *(const float4*)&sW[kk * D + 64 + tc * 4];
            float a[8];
            #pragma unroll
            for (int i = 0; i < 8; ++i) a[i] = sA[(tr * 8 + i) * 65 + kk];
            #pragma unroll
            for (int i = 0; i < 8; ++i)
                #pragma unroll
                for (int j = 0; j < 8; ++j)
                    acc[i][j] = fmaf(a[i], w[j], acc[i][j]);
        }
    };

    // prologue: chunk 0
    load_regs(A, W1, 0);
    store_lds();
    __syncthreads();
    // chunk pipeline: prefetch(c) || mma(c-1)
    load_regs(A, W1, 64);
    mma(); __syncthreads(); store_lds(); __syncthreads();
    if constexpr (DUAL) {
        load_regs(G, W2, 0);
        mma(); __syncthreads(); store_lds(); __syncthreads();
        load_regs(G, W2, 64);
        mma(); __syncthreads(); store_lds(); __syncthreads();
    }
    mma();   // last chunk

    float bc[8];
    *(float4*)&bc[0] = *(const float4*)(bias + tc * 4);
    *(float4*)&bc[4] = *(const float4*)(bias + 64 + tc * 4);

    float2 wps[8], wpd[8];
    if constexpr (PRED) {
        #pragma unroll
        for (int j = 0; j < 4; ++j) {
            wps[j]     = *(const float2*)(Wpred + (tc * 4 + j) * 2);          // ps half, cols 0-63
            wps[4 + j] = *(const float2*)(Wpred + (64 + tc * 4 + j) * 2);     // ps half, cols 64-127
            wpd[j]     = *(const float2*)(Wpred + (128 + tc * 4 + j) * 2);    // pd half
            wpd[4 + j] = *(const float2*)(Wpred + (192 + tc * 4 + j) * 2);
        }
    }

    #pragma unroll
    for (int i = 0; i < 8; ++i) {
        int row = row0 + tr * 8 + i;
        float v[8];
        float ss = 0.f;
        #pragma unroll
        for (int j = 0; j < 8; ++j) {
            float t = acc[i][j] + bc[j];
            if (RELU) t = fmaxf(t, 0.f);
            v[j] = t;
            ss += t * t;
        }
        if constexpr (L2N) {
            // row spread over 16 lanes (tc = lane bits 0-3): in-wave butterfly
            ss += __shfl_xor(ss, 1);
            ss += __shfl_xor(ss, 2);
            ss += __shfl_xor(ss, 4);
            ss += __shfl_xor(ss, 8);
            float inv = 1.0f / fmaxf(sqrtf(ss), 1e-12f);
            #pragma unroll
            for (int j = 0; j < 8; ++j) v[j] *= inv;
        }
        if constexpr (PRED) {
            float sa0 = 0.f, sa1 = 0.f, sb0 = 0.f, sb1 = 0.f;
            #pragma unroll
            for (int j = 0; j < 8; ++j) {
                sa0 = fmaf(v[j], wps[j].x, sa0);
                sa1 = fmaf(v[j], wps[j].y, sa1);
                sb0 = fmaf(v[j], wpd[j].x, sb0);
                sb1 = fmaf(v[j], wpd[j].y, sb1);
            }
            #pragma unroll
            for (int msk = 1; msk < 16; msk <<= 1) {
                sa0 += __shfl_xor(sa0, msk);
                sa1 += __shfl_xor(sa1, msk);
                sb0 += __shfl_xor(sb0, msk);
                sb1 += __shfl_xor(sb1, msk);
            }
            if (tc == 0 && row < nrows) {
                *(float2*)(ps + (size_t)row * 2) = make_float2(sa0, sa1);
                *(float2*)(pd + (size_t)row * 2) = make_float2(sb0, sb1);
            }
        } else {
            if (row < nrows) {
                *(float4*)(C + (size_t)row * D + tc * 4)      = *(float4*)&v[0];
                *(float4*)(C + (size_t)row * D + 64 + tc * 4) = *(float4*)&v[4];
            }
        }
    }
}

// ---------------- segment-max over CSR ----------------
// One wave per node; each 32-lane half handles a different in-edge with float4/lane
// (one full 512B row per half per request). cnt is wave-uniform -> no divergence.
__global__ __launch_bounds__(256) void k_aggmax(
    const float* __restrict__ m, const int* __restrict__ csr,
    const int* __restrict__ offs, const int* __restrict__ counts,
    float* __restrict__ agg, int n)
{
    int gid  = blockIdx.x * blockDim.x + threadIdx.x;
    int node = gid >> 6;
    int lane = threadIdx.x & 63;
    if (node >= n) return;
    const int start = offs[node], cnt = counts[node];
    const int half = lane >> 5;
    const float* mf = m + (lane & 31) * 4;
    float4 a0 = make_float4(0.f, 0.f, 0.f, 0.f);   // relu inputs >= 0; empty segment -> 0
    float4 a1 = make_float4(0.f, 0.f, 0.f, 0.f);
    int i = 0;
    for (; i + 4 <= cnt; i += 4) {                 // 4 rows in flight
        int s0 = csr[start + i + half];
        int s1 = csr[start + i + 2 + half];
        float4 v0 = *(const float4*)(mf + (size_t)s0 * D);
        float4 v1 = *(const float4*)(mf + (size_t)s1 * D);
        a0.x = fmaxf(a0.x, v0.x); a0.y = fmaxf(a0.y, v0.y);
        a0.z = fmaxf(a0.z, v0.z); a0.w = fmaxf(a0.w, v0.w);
        a1.x = fmaxf(a1.x, v1.x); a1.y = fmaxf(a1.y, v1.y);
        a1.z = fmaxf(a1.z, v1.z); a1.w = fmaxf(a1.w, v1.w);
    }
    if (i + 2 <= cnt) {
        int s0 = csr[start + i + half];
        float4 v0 = *(const float4*)(mf + (size_t)s0 * D);
        a0.x = fmaxf(a0.x, v0.x); a0.y = fmaxf(a0.y, v0.y);
        a0.z = fmaxf(a0.z, v0.z); a0.w = fmaxf(a0.w, v0.w);
        i += 2;
    }
    if (i < cnt) {                                  // odd tail: both halves read same row (max idempotent)
        int s0 = csr[start + i];
        float4 v0 = *(const float4*)(mf + (size_t)s0 * D);
        a0.x = fmaxf(a0.x, v0.x); a0.y = fmaxf(a0.y, v0.y);
        a0.z = fmaxf(a0.z, v0.z); a0.w = fmaxf(a0.w, v0.w);
    }
    a0.x = fmaxf(a0.x, a1.x); a0.y = fmaxf(a0.y, a1.y);
    a0.z = fmaxf(a0.z, a1.z); a0.w = fmaxf(a0.w, a1.w);
    a0.x = fmaxf(a0.x, __shfl_xor(a0.x, 32));       // merge the two halves
    a0.y = fmaxf(a0.y, __shfl_xor(a0.y, 32));
    a0.z = fmaxf(a0.z, __shfl_xor(a0.z, 32));
    a0.w = fmaxf(a0.w, __shfl_xor(a0.w, 32));
    if (half == 0)
        *(float4*)(agg + (size_t)node * D + (lane & 31) * 4) = a0;
}

// ---------------- edge scores ----------------
__global__ void k_edge(const int* __restrict__ src, const int* __restrict__ dst,
                       const float* __restrict__ ps, const float* __restrict__ pd,
                       const float* __restrict__ bpred, float* __restrict__ out, int E)
{
    int e = blockIdx.x * blockDim.x + threadIdx.x;
    if (e >= E) return;
    int s = src[e], d = dst[e];
    const float2 a = *(const float2*)(ps + 2 * (size_t)s);
    const float2 b = *(const float2*)(pd + 2 * (size_t)d);
    float2 o;
    o.x = a.x + b.x + bpred[0];
    o.y = a.y + b.y + bpred[1];
    *(float2*)(out + 2 * (size_t)e) = o;
}

extern "C" void kernel_launch(void* const* d_in, const int* in_sizes, int n_in,
                              void* d_out, int out_size, void* d_ws, size_t ws_size,
                              hipStream_t stream) {
    const float* x     = (const float*)d_in[0];
    const int*   src   = (const int*)d_in[1];
    const int*   dst   = (const int*)d_in[2];
    const float* Wp1   = (const float*)d_in[3];
    const float* bp1   = (const float*)d_in[4];
    const float* Ws1   = (const float*)d_in[5];
    const float* Wn1   = (const float*)d_in[6];
    const float* b1    = (const float*)d_in[7];
    const float* Wp2   = (const float*)d_in[8];
    const float* bp2   = (const float*)d_in[9];
    const float* Ws2   = (const float*)d_in[10];
    const float* Wn2   = (const float*)d_in[11];
    const float* b2    = (const float*)d_in[12];
    const float* Wpred = (const float*)d_in[13];
    const float* bpred = (const float*)d_in[14];
    float* out = (float*)d_out;

    const int N = in_sizes[0] / D;
    const int E = in_sizes[1];

    // workspace carve-out (~160 MB)
    char* ws = (char*)d_ws;
    size_t o = 0;
    auto carve = [&](size_t bytes) { void* p = ws + o; o += (bytes + 255) & ~(size_t)255; return p; };
    float* mbuf   = (float*)carve((size_t)N * D * 4);  // m1 / m2
    float* agg    = (float*)carve((size_t)N * D * 4);
    float* h1     = (float*)carve((size_t)N * D * 4);
    float* ps     = (float*)carve((size_t)N * 2 * 4);
    float* pd     = (float*)carve((size_t)N * 2 * 4);
    int*   counts = (int*)carve((size_t)N * 4);
    int*   cursor = (int*)carve((size_t)N * 4);
    int*   offs   = (int*)carve((size_t)N * 4);
    int*   bsum   = (int*)carve(4096);
    int*   csr    = (int*)carve((size_t)E * 4);
    (void)ws_size; (void)n_in; (void)out_size;

    hipMemsetAsync(counts, 0, (size_t)N * 4, stream);
    hipMemsetAsync(cursor, 0, (size_t)N * 4, stream);

    const int B1 = (N + 1023) / 1024;
    const int EB = (E + 255) / 256;
    const int GB = (N + 127) / 128;

    // CSR by dst
    k_count  <<<EB, 256, 0, stream>>>(dst, counts, E);
    k_scan1  <<<B1, 1024, 0, stream>>>(counts, offs, bsum, N);
    k_scan2  <<<1, 1024, 0, stream>>>(bsum, B1);
    k_scan3  <<<B1, 1024, 0, stream>>>(offs, bsum, N);
    k_scatter<<<EB, 256, 0, stream>>>(src, dst, offs, cursor, csr, E);

    // layer 1
    k_gemm<false, true, false, false><<<GB, 256, 0, stream>>>(
        x, nullptr, Wp1, nullptr, bp1, mbuf, nullptr, nullptr, nullptr, N);
    k_aggmax<<<(N + 3) / 4, 256, 0, stream>>>(mbuf, csr, offs, counts, agg, N);
    k_gemm<true, true, true, false><<<GB, 256, 0, stream>>>(
        x, agg, Ws1, Wn1, b1, h1, nullptr, nullptr, nullptr, N);

    // layer 2
    k_gemm<false, true, false, false><<<GB, 256, 0, stream>>>(
        h1, nullptr, Wp2, nullptr, bp2, mbuf, nullptr, nullptr, nullptr, N);
    k_aggmax<<<(N + 3) / 4, 256, 0, stream>>>(mbuf, csr, offs, counts, agg, N);
    // final dual GEMM: l2norm + fused edge-predictor projection; no C store
    k_gemm<true, false, true, true><<<GB, 256, 0, stream>>>(
        h1, agg, Ws2, Wn2, b2, nullptr, Wpred, ps, pd, N);

    // edge scores
    k_edge<<<EB, 256, 0, stream>>>(src, dst, ps, pd, bpred, out, E);
}

// Round 7
// 839.508 us; speedup vs baseline: 1.0972x; 1.0972x over previous
//
#include <hip/hip_runtime.h>

// GraphSAGE-pool forward. GEMMs via split-bf16 (hi+lo) 3-product MFMA on the matrix pipe.
// Pipeline: split(x), split+transpose(W*) -> CSR-build(dst)
//   -> m1=relu(x@Wp1+bp1) [MFMA, fp32 out] -> agg1=segmax(m1) [split out]
//   -> h1=l2n(relu(x@Ws1+agg1@Wn1+b1)) [MFMA dual, split out, in-place over x-planes]
//   -> m2 -> agg2 -> [h2=l2n(h1@Ws2+agg2@Wn2+b2); ps/pd=h2@Wpred] fused epilogue
//   -> score[e]=ps[src]+pd[dst]+bpred

constexpr int D = 128;

typedef short bf16x8 __attribute__((ext_vector_type(8)));
typedef float f32x4  __attribute__((ext_vector_type(4)));

__device__ __forceinline__ f32x4 mfma16(bf16x8 a, bf16x8 b, f32x4 c) {
    return __builtin_amdgcn_mfma_f32_16x16x32_bf16(a, b, c, 0, 0, 0);
}
__device__ __forceinline__ unsigned short f2bf(float x) {   // RNE fp32->bf16
    unsigned int u = __float_as_uint(x);
    u += 0x7FFFu + ((u >> 16) & 1u);
    return (unsigned short)(u >> 16);
}
__device__ __forceinline__ float bf2f(unsigned short h) {
    return __uint_as_float(((unsigned int)h) << 16);
}

// ---------------- prep: split x into hi/lo bf16 planes ----------------
__global__ __launch_bounds__(256) void k_split(const float* __restrict__ x,
                                               short* __restrict__ xh, short* __restrict__ xl, int n4) {
    int i = blockIdx.x * blockDim.x + threadIdx.x;
    if (i >= n4) return;
    float4 v = ((const float4*)x)[i];
    short4 h, l;
    {  unsigned short hh = f2bf(v.x); h.x = (short)hh; l.x = (short)f2bf(v.x - bf2f(hh)); }
    {  unsigned short hh = f2bf(v.y); h.y = (short)hh; l.y = (short)f2bf(v.y - bf2f(hh)); }
    {  unsigned short hh = f2bf(v.z); h.z = (short)hh; l.z = (short)f2bf(v.z - bf2f(hh)); }
    {  unsigned short hh = f2bf(v.w); h.w = (short)hh; l.w = (short)f2bf(v.w - bf2f(hh)); }
    ((short4*)xh)[i] = h;
    ((short4*)xl)[i] = l;
}

// ---------------- prep: transpose + split the 6 128x128 weight matrices ----------------
struct WArgs { const float* s[6]; short* h[6]; short* l[6]; };
__global__ __launch_bounds__(256) void k_wsplit(WArgs a) {
    __shared__ float sw[128 * 129];
    const int m = blockIdx.x, tid = threadIdx.x;
    const float* src = a.s[m];
    #pragma unroll
    for (int it = 0; it < 16; ++it) {               // 4096 float4 = 16384 floats
        int idx = it * 256 + tid;
        float4 v = ((const float4*)src)[idx];
        int k = idx >> 5, n4 = (idx & 31) * 4;      // W[k][n] row-major
        sw[k * 129 + n4 + 0] = v.x; sw[k * 129 + n4 + 1] = v.y;
        sw[k * 129 + n4 + 2] = v.z; sw[k * 129 + n4 + 3] = v.w;
    }
    __syncthreads();
    short* __restrict__ dh = a.h[m];
    short* __restrict__ dl = a.l[m];
    #pragma unroll
    for (int it = 0; it < 64; ++it) {
        int idx = it * 256 + tid;
        int n = idx >> 7, k = idx & 127;            // WT[n][k]
        float v = sw[k * 129 + n];
        unsigned short hh = f2bf(v);
        dh[n * 128 + k] = (short)hh;
        dl[n * 128 + k] = (short)f2bf(v - bf2f(hh));
    }
}

// ---------------- CSR build ----------------
__global__ void k_count(const int* __restrict__ dst, int* __restrict__ counts, int E) {
    int e = blockIdx.x * blockDim.x + threadIdx.x;
    if (e < E) atomicAdd(&counts[dst[e]], 1);
}
__global__ void k_scan1(const int* __restrict__ counts, int* __restrict__ offs,
                        int* __restrict__ bsum, int n) {
    __shared__ int sh[1024];
    int tid = threadIdx.x;
    int i = blockIdx.x * 1024 + tid;
    int c = (i < n) ? counts[i] : 0;
    sh[tid] = c;
    __syncthreads();
    for (int off = 1; off < 1024; off <<= 1) {
        int v = (tid >= off) ? sh[tid - off] : 0;
        __syncthreads();
        sh[tid] += v;
        __syncthreads();
    }
    if (i < n) offs[i] = sh[tid] - c;
    if (tid == 1023) bsum[blockIdx.x] = sh[1023];
}
__global__ void k_scan2(int* __restrict__ bsum, int nb) {
    __shared__ int sh[1024];
    int tid = threadIdx.x;
    int c = (tid < nb) ? bsum[tid] : 0;
    sh[tid] = c;
    __syncthreads();
    for (int off = 1; off < 1024; off <<= 1) {
        int v = (tid >= off) ? sh[tid - off] : 0;
        __syncthreads();
        sh[tid] += v;
        __syncthreads();
    }
    if (tid < nb) bsum[tid] = sh[tid] - c;
}
__global__ void k_scan3(int* __restrict__ offs, const int* __restrict__ bsum, int n) {
    int i = blockIdx.x * 1024 + threadIdx.x;
    if (i < n) offs[i] += bsum[blockIdx.x];
}
__global__ void k_scatter(const int* __restrict__ src, const int* __restrict__ dst,
                          const int* __restrict__ offs, int* __restrict__ cursor,
                          int* __restrict__ csr, int E) {
    int e = blockIdx.x * blockDim.x + threadIdx.x;
    if (e < E) {
        int d = dst[e];
        int pos = offs[d] + atomicAdd(&cursor[d], 1);
        csr[pos] = src[e];
    }
}

// ---------------- split-bf16 MFMA GEMM ----------------
// C = act(A@W1 [+ G@W2] + bias). 128x128 tile, 4 waves (2x2), 16x16x32 bf16 MFMA.
// Split-2: acc += Ah*Wh + Ah*Wl + Al*Wh. K chunked by 64; LDS 4 planes x 16KB = 64KB -> 2 blk/CU.
// LDS layout per plane: [128 rows][64 k] bf16, phys = row*128B + (kbyte ^ ((row&7)<<4)) (T2 swizzle).
// Read applies the same XOR (row&7 == lrow&7 for all wave sub-tiles) -> logical k contiguous.
// MODE 0: relu -> Cm fp32. MODE 1: relu+l2norm -> split store Oh/Ol (may alias A planes:
// no __restrict__ on A/O). MODE 2: l2norm + fused edge-predictor projection -> ps/pd, no C store.
template<bool DUAL, int MODE>
__global__ __launch_bounds__(256, 2) void k_mgemm(
    const short* AhP, const short* AlP,
    const short* GhP, const short* GlP,
    const short* __restrict__ W1h, const short* __restrict__ W1l,
    const short* __restrict__ W2h, const short* __restrict__ W2l,
    const float* __restrict__ bias, float* __restrict__ Cm,
    short* Oh, short* Ol,
    const float* __restrict__ Wpred, float* __restrict__ ps, float* __restrict__ pd,
    int nrows)
{
    __shared__ short smem[4 * 8192];     // planes: sAh, sAl, sWh, sWl (16KB each)
    const int tid  = threadIdx.x;
    const int lane = tid & 63;
    const int w    = tid >> 6;
    const int wr   = w >> 1, wc = w & 1;           // wave tile: rows wr*64.., cols wc*64..
    const int lrow = lane & 15, g = lane >> 4;
    const int row0 = blockIdx.x * 128;

    // per-lane constant frag offsets (bytes within a plane)
    const int xr   = (lrow & 7) << 4;
    const int aoff = (wr * 64 + lrow) * 128;
    const int woff = (wc * 64 + lrow) * 128;
    const int kx[2] = { (g * 16) ^ xr, (64 + g * 16) ^ xr };

    f32x4 acc[4][4];
    #pragma unroll
    for (int i = 0; i < 4; ++i)
        #pragma unroll
        for (int j = 0; j < 4; ++j) acc[i][j] = (f32x4){0.f, 0.f, 0.f, 0.f};

    constexpr int NCH = DUAL ? 4 : 2;
    const short* aSrcH[4] = { AhP, AhP, GhP, GhP };
    const short* aSrcL[4] = { AlP, AlP, GlP, GlP };
    const short* wSrcH[4] = { W1h, W1h, W2h, W2h };
    const short* wSrcL[4] = { W1l, W1l, W2l, W2l };
    const int    k0s[4]   = { 0, 64, 0, 64 };

    uint4 rg[16];

    auto loadreg = [&](int c) {
        #pragma unroll
        for (int p = 0; p < 4; ++p)
            #pragma unroll
            for (int i = 0; i < 4; ++i) {
                int cidx = i * 256 + tid;
                int row = cidx >> 3, kc = (cidx & 7) * 8;
                const short* srcb =
                    (p == 0) ? aSrcH[c] + (size_t)(row0 + row) * D :
                    (p == 1) ? aSrcL[c] + (size_t)(row0 + row) * D :
                    (p == 2) ? wSrcH[c] + (size_t)row * D :
                               wSrcL[c] + (size_t)row * D;
                rg[p * 4 + i] = *(const uint4*)(srcb + k0s[c] + kc);
            }
    };
    auto ldswrite = [&]() {
        #pragma unroll
        for (int p = 0; p < 4; ++p)
            #pragma unroll
            for (int i = 0; i < 4; ++i) {
                int cidx = i * 256 + tid;
                int row = cidx >> 3, kb = (cidx & 7) * 16;
                char* dstb = (char*)smem + p * 16384 + row * 128 + (kb ^ ((row & 7) << 4));
                *(uint4*)dstb = rg[p * 4 + i];
            }
    };
    auto mma = [&]() {
        const char* base = (const char*)smem;
        #pragma unroll
        for (int ks = 0; ks < 2; ++ks) {
            bf16x8 ah[4], al[4], wh[4], wl[4];
            #pragma unroll
            for (int t = 0; t < 4; ++t) {
                ah[t] = *(const bf16x8*)(base +         aoff + t * 2048 + kx[ks]);
                al[t] = *(const bf16x8*)(base + 16384 + aoff + t * 2048 + kx[ks]);
                wh[t] = *(const bf16x8*)(base + 32768 + woff + t * 2048 + kx[ks]);
                wl[t] = *(const bf16x8*)(base + 49152 + woff + t * 2048 + kx[ks]);
            }
            #pragma unroll
            for (int rt = 0; rt < 4; ++rt)
                #pragma unroll
                for (int ct = 0; ct < 4; ++ct) {
                    acc[rt][ct] = mfma16(ah[rt], wh[ct], acc[rt][ct]);
                    acc[rt][ct] = mfma16(ah[rt], wl[ct], acc[rt][ct]);
                    acc[rt][ct] = mfma16(al[rt], wh[ct], acc[rt][ct]);
                }
        }
    };

    // pipeline: issue chunk c's loads before mma(c-1)
    loadreg(0);
    ldswrite();
    __syncthreads();
    #pragma unroll
    for (int c = 1; c < NCH; ++c) {
        loadreg(c);
        mma();
        __syncthreads();
        ldswrite();
        __syncthreads();
    }
    mma();

    float bcol[4];
    #pragma unroll
    for (int ct = 0; ct < 4; ++ct) bcol[ct] = bias[wc * 64 + ct * 16 + lrow];

    if constexpr (MODE == 0) {
        #pragma unroll
        for (int rt = 0; rt < 4; ++rt)
            #pragma unroll
            for (int j = 0; j < 4; ++j) {
                int R = row0 + wr * 64 + rt * 16 + g * 4 + j;
                if (R < nrows) {
                    #pragma unroll
                    for (int ct = 0; ct < 4; ++ct) {
                        int col = wc * 64 + ct * 16 + lrow;
                        Cm[(size_t)R * D + col] = fmaxf(acc[rt][ct][j] + bcol[ct], 0.f);
                    }
                }
            }
    } else if constexpr (MODE == 1) {
        __syncthreads();                        // smem reuse for cross-wave row sums
        float* ssb = (float*)smem;              // [2 wc][128 rows]
        #pragma unroll
        for (int rt = 0; rt < 4; ++rt)
            #pragma unroll
            for (int j = 0; j < 4; ++j) {
                float ss = 0.f;
                #pragma unroll
                for (int ct = 0; ct < 4; ++ct) {
                    float v = fmaxf(acc[rt][ct][j] + bcol[ct], 0.f);
                    acc[rt][ct][j] = v;
                    ss += v * v;
                }
                ss += __shfl_xor(ss, 1); ss += __shfl_xor(ss, 2);
                ss += __shfl_xor(ss, 4); ss += __shfl_xor(ss, 8);
                if (lrow == 0) ssb[wc * 128 + wr * 64 + rt * 16 + g * 4 + j] = ss;
            }
        __syncthreads();
        #pragma unroll
        for (int rt = 0; rt < 4; ++rt)
            #pragma unroll
            for (int j = 0; j < 4; ++j) {
                int r = wr * 64 + rt * 16 + g * 4 + j;
                int R = row0 + r;
                float tot = ssb[r] + ssb[128 + r];
                float inv = 1.f / fmaxf(sqrtf(tot), 1e-12f);
                if (R < nrows) {
                    #pragma unroll
                    for (int ct = 0; ct < 4; ++ct) {
                        int col = wc * 64 + ct * 16 + lrow;
                        float v = acc[rt][ct][j] * inv;
                        unsigned short hh = f2bf(v);
                        Oh[(size_t)R * D + col] = (short)hh;
                        Ol[(size_t)R * D + col] = (short)f2bf(v - bf2f(hh));
                    }
                }
            }
    } else {                                    // MODE 2: l2norm + predictor projection
        float2 wpsv[4], wpdv[4];
        #pragma unroll
        for (int ct = 0; ct < 4; ++ct) {
            int col = wc * 64 + ct * 16 + lrow;
            wpsv[ct] = *(const float2*)(Wpred + col * 2);
            wpdv[ct] = *(const float2*)(Wpred + (128 + col) * 2);
        }
        __syncthreads();
        float* pb = (float*)smem;               // [(wc*128 + r)*5 + q]
        #pragma unroll
        for (int rt = 0; rt < 4; ++rt)
            #pragma unroll
            for (int j = 0; j < 4; ++j) {
                float ss = 0.f, sa0 = 0.f, sa1 = 0.f, sb0 = 0.f, sb1 = 0.f;
                #pragma unroll
                for (int ct = 0; ct < 4; ++ct) {
                    float v = acc[rt][ct][j] + bcol[ct];     // no relu in layer-2 output
                    ss  += v * v;
                    sa0 = fmaf(v, wpsv[ct].x, sa0); sa1 = fmaf(v, wpsv[ct].y, sa1);
                    sb0 = fmaf(v, wpdv[ct].x, sb0); sb1 = fmaf(v, wpdv[ct].y, sb1);
                }
                #pragma unroll
                for (int msk = 1; msk < 16; msk <<= 1) {
                    ss  += __shfl_xor(ss, msk);
                    sa0 += __shfl_xor(sa0, msk); sa1 += __shfl_xor(sa1, msk);
                    sb0 += __shfl_xor(sb0, msk); sb1 += __shfl_xor(sb1, msk);
                }
                if (lrow == 0) {
                    int r = wr * 64 + rt * 16 + g * 4 + j;
                    float* q = pb + (wc * 128 + r) * 5;
                    q[0] = ss; q[1] = sa0; q[2] = sa1; q[3] = sb0; q[4] = sb1;
                }
            }
        __syncthreads();
        if (tid < 128) {
            int R = row0 + tid;
            if (R < nrows) {
                const float* q0 = pb + tid * 5;
                const float* q1 = pb + (128 + tid) * 5;
                float inv = 1.f / fmaxf(sqrtf(q0[0] + q1[0]), 1e-12f);
                ps[(size_t)R * 2 + 0] = inv * (q0[1] + q1[1]);
                ps[(size_t)R * 2 + 1] = inv * (q0[2] + q1[2]);
                pd[(size_t)R * 2 + 0] = inv * (q0[3] + q1[3]);
                pd[(size_t)R * 2 + 1] = inv * (q0[4] + q1[4]);
            }
        }
    }
}

// ---------------- segment-max over CSR; epilogue splits agg into hi/lo bf16 ----------------
__global__ __launch_bounds__(256) void k_aggmax(
    const float* __restrict__ m, const int* __restrict__ csr,
    const int* __restrict__ offs, const int* __restrict__ counts,
    short* __restrict__ aggh, short* __restrict__ aggl, int n)
{
    int gid  = blockIdx.x * blockDim.x + threadIdx.x;
    int node = gid >> 6;
    int lane = threadIdx.x & 63;
    if (node >= n) return;
    const int start = offs[node], cnt = counts[node];
    const int half = lane >> 5;
    const float* mf = m + (lane & 31) * 4;
    float4 a0 = make_float4(0.f, 0.f, 0.f, 0.f);   // relu inputs >= 0; empty segment -> 0
    float4 a1 = make_float4(0.f, 0.f, 0.f, 0.f);
    int i = 0;
    for (; i + 4 <= cnt; i += 4) {
        int s0 = csr[start + i + half];
        int s1 = csr[start + i + 2 + half];
        float4 v0 = *(const float4*)(mf + (size_t)s0 * D);
        float4 v1 = *(const float4*)(mf + (size_t)s1 * D);
        a0.x = fmaxf(a0.x, v0.x); a0.y = fmaxf(a0.y, v0.y);
        a0.z = fmaxf(a0.z, v0.z); a0.w = fmaxf(a0.w, v0.w);
        a1.x = fmaxf(a1.x, v1.x); a1.y = fmaxf(a1.y, v1.y);
        a1.z = fmaxf(a1.z, v1.z); a1.w = fmaxf(a1.w, v1.w);
    }
    if (i + 2 <= cnt) {
        int s0 = csr[start + i + half];
        float4 v0 = *(const float4*)(mf + (size_t)s0 * D);
        a0.x = fmaxf(a0.x, v0.x); a0.y = fmaxf(a0.y, v0.y);
        a0.z = fmaxf(a0.z, v0.z); a0.w = fmaxf(a0.w, v0.w);
        i += 2;
    }
    if (i < cnt) {                                  // odd tail: both halves same row (idempotent)
        int s0 = csr[start + i];
        float4 v0 = *(const float4*)(mf + (size_t)s0 * D);
        a0.x = fmaxf(a0.x, v0.x); a0.y = fmaxf(a0.y, v0.y);
        a0.z = fmaxf(a0.z, v0.z); a0.w = fmaxf(a0.w, v0.w);
    }
    a0.x = fmaxf(a0.x, a1.x); a0.y = fmaxf(a0.y, a1.y);
    a0.z = fmaxf(a0.z, a1.z); a0.w = fmaxf(a0.w, a1.w);
    a0.x = fmaxf(a0.x, __shfl_xor(a0.x, 32));
    a0.y = fmaxf(a0.y, __shfl_xor(a0.y, 32));
    a0.z = fmaxf(a0.z, __shfl_xor(a0.z, 32));
    a0.w = fmaxf(a0.w, __shfl_xor(a0.w, 32));
    if (half == 0) {
        size_t base = (size_t)node * D + (lane & 31) * 4;
        float vv[4] = { a0.x, a0.y, a0.z, a0.w };
        short4 hv, lv;
        {   unsigned short hh = f2bf(vv[0]); hv.x = (short)hh; lv.x = (short)f2bf(vv[0] - bf2f(hh)); }
        {   unsigned short hh = f2bf(vv[1]); hv.y = (short)hh; lv.y = (short)f2bf(vv[1] - bf2f(hh)); }
        {   unsigned short hh = f2bf(vv[2]); hv.z = (short)hh; lv.z = (short)f2bf(vv[2] - bf2f(hh)); }
        {   unsigned short hh = f2bf(vv[3]); hv.w = (short)hh; lv.w = (short)f2bf(vv[3] - bf2f(hh)); }
        *(short4*)(aggh + base) = hv;
        *(short4*)(aggl + base) = lv;
    }
}

// ---------------- edge scores ----------------
__global__ void k_edge(const int* __restrict__ src, const int* __restrict__ dst,
                       const float* __restrict__ ps, const float* __restrict__ pd,
                       const float* __restrict__ bpred, float* __restrict__ out, int E)
{
    int e = blockIdx.x * blockDim.x + threadIdx.x;
    if (e >= E) return;
    int s = src[e], d = dst[e];
    const float2 a = *(const float2*)(ps + 2 * (size_t)s);
    const float2 b = *(const float2*)(pd + 2 * (size_t)d);
    float2 o;
    o.x = a.x + b.x + bpred[0];
    o.y = a.y + b.y + bpred[1];
    *(float2*)(out + 2 * (size_t)e) = o;
}

extern "C" void kernel_launch(void* const* d_in, const int* in_sizes, int n_in,
                              void* d_out, int out_size, void* d_ws, size_t ws_size,
                              hipStream_t stream) {
    const float* x     = (const float*)d_in[0];
    const int*   src   = (const int*)d_in[1];
    const int*   dst   = (const int*)d_in[2];
    const float* Wp1   = (const float*)d_in[3];
    const float* bp1   = (const float*)d_in[4];
    const float* Ws1   = (const float*)d_in[5];
    const float* Wn1   = (const float*)d_in[6];
    const float* b1    = (const float*)d_in[7];
    const float* Wp2   = (const float*)d_in[8];
    const float* bp2   = (const float*)d_in[9];
    const float* Ws2   = (const float*)d_in[10];
    const float* Wn2   = (const float*)d_in[11];
    const float* b2    = (const float*)d_in[12];
    const float* Wpred = (const float*)d_in[13];
    const float* bpred = (const float*)d_in[14];
    float* out = (float*)d_out;

    const int N  = in_sizes[0] / D;
    const int E  = in_sizes[1];
    const int NP = ((N + 127) / 128) * 128 + 128;   // padded rows (staging reads past tail)

    char* ws = (char*)d_ws;
    size_t o = 0;
    auto carve = [&](size_t bytes) { void* p = ws + o; o += (bytes + 255) & ~(size_t)255; return p; };
    short* xh    = (short*)carve((size_t)NP * D * 2);   // becomes h1h in-place
    short* xl    = (short*)carve((size_t)NP * D * 2);   // becomes h1l in-place
    short* aggh  = (short*)carve((size_t)NP * D * 2);
    short* aggl  = (short*)carve((size_t)NP * D * 2);
    float* mbuf  = (float*)carve((size_t)N * D * 4);    // m1 / m2 (fp32, aggmax input)
    short* wth   = (short*)carve((size_t)6 * D * D * 2);
    short* wtl   = (short*)carve((size_t)6 * D * D * 2);
    float* ps    = (float*)carve((size_t)N * 2 * 4);
    float* pd    = (float*)carve((size_t)N * 2 * 4);
    int*   counts= (int*)carve((size_t)N * 4);
    int*   cursor= (int*)carve((size_t)N * 4);
    int*   offs  = (int*)carve((size_t)N * 4);
    int*   bsum  = (int*)carve(4096);
    int*   csr   = (int*)carve((size_t)E * 4);
    (void)ws_size; (void)n_in; (void)out_size;

    hipMemsetAsync(counts, 0, (size_t)N * 4, stream);
    hipMemsetAsync(cursor, 0, (size_t)N * 4, stream);

    // prep: splits
    const int n4 = N * D / 4;
    k_split<<<(n4 + 255) / 256, 256, 0, stream>>>(x, xh, xl, n4);
    WArgs wa;
    const float* wsrc[6] = { Wp1, Ws1, Wn1, Wp2, Ws2, Wn2 };
    for (int i = 0; i < 6; ++i) {
        wa.s[i] = wsrc[i];
        wa.h[i] = wth + (size_t)i * D * D;
        wa.l[i] = wtl + (size_t)i * D * D;
    }
    k_wsplit<<<6, 256, 0, stream>>>(wa);

    const int B1 = (N + 1023) / 1024;
    const int EB = (E + 255) / 256;
    const int GB = (N + 127) / 128;

    // CSR by dst
    k_count  <<<EB, 256, 0, stream>>>(dst, counts, E);
    k_scan1  <<<B1, 1024, 0, stream>>>(counts, offs, bsum, N);
    k_scan2  <<<1, 1024, 0, stream>>>(bsum, B1);
    k_scan3  <<<B1, 1024, 0, stream>>>(offs, bsum, N);
    k_scatter<<<EB, 256, 0, stream>>>(src, dst, offs, cursor, csr, E);

    short* Wp1h = wa.h[0]; short* Wp1l = wa.l[0];
    short* Ws1h = wa.h[1]; short* Ws1l = wa.l[1];
    short* Wn1h = wa.h[2]; short* Wn1l = wa.l[2];
    short* Wp2h = wa.h[3]; short* Wp2l = wa.l[3];
    short* Ws2h = wa.h[4]; short* Ws2l = wa.l[4];
    short* Wn2h = wa.h[5]; short* Wn2l = wa.l[5];

    // layer 1
    k_mgemm<false, 0><<<GB, 256, 0, stream>>>(xh, xl, nullptr, nullptr, Wp1h, Wp1l, nullptr, nullptr,
                                              bp1, mbuf, nullptr, nullptr, nullptr, nullptr, nullptr, N);
    k_aggmax<<<(N + 3) / 4, 256, 0, stream>>>(mbuf, csr, offs, counts, aggh, aggl, N);
    // h1 written in-place over xh/xl (row-ranges are block-local; A fully staged before epilogue)
    k_mgemm<true, 1><<<GB, 256, 0, stream>>>(xh, xl, aggh, aggl, Ws1h, Ws1l, Wn1h, Wn1l,
                                             b1, nullptr, xh, xl, nullptr, nullptr, nullptr, N);
    // layer 2
    k_mgemm<false, 0><<<GB, 256, 0, stream>>>(xh, xl, nullptr, nullptr, Wp2h, Wp2l, nullptr, nullptr,
                                              bp2, mbuf, nullptr, nullptr, nullptr, nullptr, nullptr, N);
    k_aggmax<<<(N + 3) / 4, 256, 0, stream>>>(mbuf, csr, offs, counts, aggh, aggl, N);
    k_mgemm<true, 2><<<GB, 256, 0, stream>>>(xh, xl, aggh, aggl, Ws2h, Ws2l, Wn2h, Wn2l,
                                             b2, nullptr, nullptr, nullptr, Wpred, ps, pd, N);

    // edge scores
    k_edge<<<EB, 256, 0, stream>>>(src, dst, ps, pd, bpred, out, E);
}

// Round 11
// 592.464 us; speedup vs baseline: 1.5548x; 1.4170x over previous
//
#include <hip/hip_runtime.h>

// GraphSAGE-pool forward. GEMMs: split-bf16 (hi+lo) MFMA; staging via global_load_lds(16B)
// with pre-inverse-swizzled per-lane global sources (LDS dest is lane-linear).
// m-plane and agg are bf16 (max commutes with monotone RNE -> agg_h exact; residual dropped).
// Pipeline: split(x), split+transpose(W*) -> CSR-build(dst)
//   -> m1=relu(x@Wp1+bp1)->bf16 -> agg1=segmax_bf16 -> h1=l2n(relu(x@Ws1+agg1@Wn1+b1)) split,in-place
//   -> m2 -> agg2 -> [h2=l2n(h1@Ws2+agg2@Wn2+b2); ps/pd=h2@Wpred] fused -> score[e]

constexpr int D = 128;

typedef short bf16x8 __attribute__((ext_vector_type(8)));
typedef float f32x4  __attribute__((ext_vector_type(4)));
typedef unsigned int u32;

__device__ __forceinline__ f32x4 mfma16(bf16x8 a, bf16x8 b, f32x4 c) {
    return __builtin_amdgcn_mfma_f32_16x16x32_bf16(a, b, c, 0, 0, 0);
}
__device__ __forceinline__ unsigned short f2bf(float x) {   // RNE fp32->bf16
    unsigned int u = __float_as_uint(x);
    u += 0x7FFFu + ((u >> 16) & 1u);
    return (unsigned short)(u >> 16);
}
__device__ __forceinline__ float bf2f(unsigned short h) {
    return __uint_as_float(((unsigned int)h) << 16);
}
__device__ __forceinline__ void gld_lds16(const short* g, short* l) {
    __builtin_amdgcn_global_load_lds((const __attribute__((address_space(1))) u32*)g,
                                     (__attribute__((address_space(3))) u32*)l, 16, 0, 0);
}
// packed max of 2x u16 (valid bf16 ordering for nonneg values)
__device__ __forceinline__ unsigned pmaxu16(unsigned a, unsigned b) {
    unsigned ah = a & 0xFFFF0000u, bh = b & 0xFFFF0000u;
    unsigned al = a & 0x0000FFFFu, bl = b & 0x0000FFFFu;
    return (ah >= bh ? ah : bh) | (al >= bl ? al : bl);
}

// ---------------- prep: split x into hi/lo bf16 planes ----------------
__global__ __launch_bounds__(256) void k_split(const float* __restrict__ x,
                                               short* __restrict__ xh, short* __restrict__ xl, int n4) {
    int i = blockIdx.x * blockDim.x + threadIdx.x;
    if (i >= n4) return;
    float4 v = ((const float4*)x)[i];
    short4 h, l;
    {  unsigned short hh = f2bf(v.x); h.x = (short)hh; l.x = (short)f2bf(v.x - bf2f(hh)); }
    {  unsigned short hh = f2bf(v.y); h.y = (short)hh; l.y = (short)f2bf(v.y - bf2f(hh)); }
    {  unsigned short hh = f2bf(v.z); h.z = (short)hh; l.z = (short)f2bf(v.z - bf2f(hh)); }
    {  unsigned short hh = f2bf(v.w); h.w = (short)hh; l.w = (short)f2bf(v.w - bf2f(hh)); }
    ((short4*)xh)[i] = h;
    ((short4*)xl)[i] = l;
}

// ---------------- prep: transpose + split the 6 128x128 weight matrices ----------------
struct WArgs { const float* s[6]; short* h[6]; short* l[6]; };
__global__ __launch_bounds__(256) void k_wsplit(WArgs a) {
    __shared__ float sw[128 * 129];
    const int m = blockIdx.x, tid = threadIdx.x;
    const float* src = a.s[m];
    #pragma unroll
    for (int it = 0; it < 16; ++it) {
        int idx = it * 256 + tid;
        float4 v = ((const float4*)src)[idx];
        int k = idx >> 5, n4 = (idx & 31) * 4;      // W[k][n] row-major
        sw[k * 129 + n4 + 0] = v.x; sw[k * 129 + n4 + 1] = v.y;
        sw[k * 129 + n4 + 2] = v.z; sw[k * 129 + n4 + 3] = v.w;
    }
    __syncthreads();
    short* __restrict__ dh = a.h[m];
    short* __restrict__ dl = a.l[m];
    #pragma unroll
    for (int it = 0; it < 64; ++it) {
        int idx = it * 256 + tid;
        int n = idx >> 7, k = idx & 127;            // WT[n][k]
        float v = sw[k * 129 + n];
        unsigned short hh = f2bf(v);
        dh[n * 128 + k] = (short)hh;
        dl[n * 128 + k] = (short)f2bf(v - bf2f(hh));
    }
}

// ---------------- CSR build ----------------
__global__ void k_count(const int* __restrict__ dst, int* __restrict__ counts, int E) {
    int e = blockIdx.x * blockDim.x + threadIdx.x;
    if (e < E) atomicAdd(&counts[dst[e]], 1);
}
__global__ void k_scan1(const int* __restrict__ counts, int* __restrict__ offs,
                        int* __restrict__ bsum, int n) {
    __shared__ int sh[1024];
    int tid = threadIdx.x;
    int i = blockIdx.x * 1024 + tid;
    int c = (i < n) ? counts[i] : 0;
    sh[tid] = c;
    __syncthreads();
    for (int off = 1; off < 1024; off <<= 1) {
        int v = (tid >= off) ? sh[tid - off] : 0;
        __syncthreads();
        sh[tid] += v;
        __syncthreads();
    }
    if (i < n) offs[i] = sh[tid] - c;
    if (tid == 1023) bsum[blockIdx.x] = sh[1023];
}
__global__ void k_scan2(int* __restrict__ bsum, int nb) {
    __shared__ int sh[1024];
    int tid = threadIdx.x;
    int c = (tid < nb) ? bsum[tid] : 0;
    sh[tid] = c;
    __syncthreads();
    for (int off = 1; off < 1024; off <<= 1) {
        int v = (tid >= off) ? sh[tid - off] : 0;
        __syncthreads();
        sh[tid] += v;
        __syncthreads();
    }
    if (tid < nb) bsum[tid] = sh[tid] - c;
}
__global__ void k_scan3(int* __restrict__ offs, const int* __restrict__ bsum, int n) {
    int i = blockIdx.x * 1024 + threadIdx.x;
    if (i < n) offs[i] += bsum[blockIdx.x];
}
// single atomic per edge: offs[d] becomes END offset; aggmax recovers start = offs - counts
__global__ void k_scatter(const int* __restrict__ src, const int* __restrict__ dst,
                          int* __restrict__ offs, int* __restrict__ csr, int E) {
    int e = blockIdx.x * blockDim.x + threadIdx.x;
    if (e < E) {
        int pos = atomicAdd(&offs[dst[e]], 1);
        csr[pos] = src[e];
    }
}

// ---------------- split-bf16 MFMA GEMM ----------------
// C = act(A@W1 [+ G@W2] + bias). 128x128 tile, 4 waves (2x2), 16x16x32 bf16 MFMA.
// A chunks (c<2): 3 products Ah*Wh + Ah*Wl + Al*Wh. G chunks (c>=2): 2 products (G is bf16-only).
// K chunked by 64; LDS 4 planes x 16KB = 64KB -> 2 blk/CU. Staging: global_load_lds w16,
// lane-linear LDS dest + pre-inverse-swizzled global src (phys kb = kb ^ ((row&7)<<4)).
// MODE 0: relu -> bf16 Mh. MODE 1: relu+l2norm -> split Oh/Ol (alias A planes; no __restrict__).
// MODE 2: l2norm + fused edge-predictor projection -> ps/pd, no C store.
template<bool DUAL, int MODE>
__global__ __launch_bounds__(256, 2) void k_mgemm(
    const short* AhP, const short* AlP, const short* GhP,
    const short* __restrict__ W1h, const short* __restrict__ W1l,
    const short* __restrict__ W2h, const short* __restrict__ W2l,
    const float* __restrict__ bias, short* Mh,
    short* Oh, short* Ol,
    const float* __restrict__ Wpred, float* __restrict__ ps, float* __restrict__ pd,
    int nrows)
{
    __shared__ short smem[4 * 8192];     // planes: sAh, sAl, sWh, sWl (16KB each)
    const int tid  = threadIdx.x;
    const int lane = tid & 63;
    const int w    = tid >> 6;
    const int wr   = w >> 1, wc = w & 1;
    const int lrow = lane & 15, g = lane >> 4;
    const int row0 = blockIdx.x * 128;

    const int xr   = (lrow & 7) << 4;
    const int aoff = (wr * 64 + lrow) * 128;     // bytes
    const int woff = (wc * 64 + lrow) * 128;
    const int kx[2] = { (g * 16) ^ xr, (64 + g * 16) ^ xr };

    f32x4 acc[4][4];
    #pragma unroll
    for (int i = 0; i < 4; ++i)
        #pragma unroll
        for (int j = 0; j < 4; ++j) acc[i][j] = (f32x4){0.f, 0.f, 0.f, 0.f};

    constexpr int NCH = DUAL ? 4 : 2;
    const short* aH[4]  = { AhP, AhP, GhP, GhP };
    const short* aL[4]  = { AlP, AlP, AlP, AlP };     // unused for c>=2
    const short* wHs[4] = { W1h, W1h, W2h, W2h };
    const short* wLs[4] = { W1l, W1l, W2l, W2l };
    const int    k0s[4] = { 0, 64, 0, 64 };

    auto issue = [&](int c, bool lo) {
        #pragma unroll
        for (int i = 0; i < 4; ++i) {
            int cidx = i * 256 + tid;
            int row  = cidx >> 3;
            int ks   = ((cidx & 7) * 8) ^ ((row & 7) << 3);   // shorts, pre-inverse-swizzled
            int lsl  = (i * 256 + (tid & 192)) * 8;           // wave-uniform LDS short slot
            size_t arow = (size_t)(row0 + row) * 128 + k0s[c] + ks;
            size_t wrow = (size_t)row * 128 + k0s[c] + ks;
            gld_lds16(aH[c] + arow, smem + lsl);
            if (lo) gld_lds16(aL[c] + arow, smem + 8192 + lsl);
            gld_lds16(wHs[c] + wrow, smem + 16384 + lsl);
            gld_lds16(wLs[c] + wrow, smem + 24576 + lsl);
        }
    };
    auto mma = [&](bool lo) {
        const char* base = (const char*)smem;
        #pragma unroll
        for (int ks = 0; ks < 2; ++ks) {
            bf16x8 ah[4], al[4], wh[4], wl[4];
            #pragma unroll
            for (int t = 0; t < 4; ++t) {
                ah[t] = *(const bf16x8*)(base +         aoff + t * 2048 + kx[ks]);
                if (lo) al[t] = *(const bf16x8*)(base + 16384 + aoff + t * 2048 + kx[ks]);
                wh[t] = *(const bf16x8*)(base + 32768 + woff + t * 2048 + kx[ks]);
                wl[t] = *(const bf16x8*)(base + 49152 + woff + t * 2048 + kx[ks]);
            }
            #pragma unroll
            for (int rt = 0; rt < 4; ++rt)
                #pragma unroll
                for (int ct = 0; ct < 4; ++ct) {
                    acc[rt][ct] = mfma16(ah[rt], wh[ct], acc[rt][ct]);
                    acc[rt][ct] = mfma16(ah[rt], wl[ct], acc[rt][ct]);
                    if (lo) acc[rt][ct] = mfma16(al[rt], wh[ct], acc[rt][ct]);
                }
        }
    };

    // m97-style: 2 barriers per chunk; cross-block overlap (2 blk/CU) hides the drain
    issue(0, true);
    __syncthreads();
    #pragma unroll
    for (int c = 1; c < NCH; ++c) {
        mma((c - 1) < 2);
        __syncthreads();
        issue(c, c < 2);
        __syncthreads();
    }
    mma((NCH - 1) < 2);

    float bcol[4];
    #pragma unroll
    for (int ct = 0; ct < 4; ++ct) bcol[ct] = bias[wc * 64 + ct * 16 + lrow];

    if constexpr (MODE == 0) {
        #pragma unroll
        for (int rt = 0; rt < 4; ++rt)
            #pragma unroll
            for (int j = 0; j < 4; ++j) {
                int R = row0 + wr * 64 + rt * 16 + g * 4 + j;
                if (R < nrows) {
                    #pragma unroll
                    for (int ct = 0; ct < 4; ++ct) {
                        int col = wc * 64 + ct * 16 + lrow;
                        Mh[(size_t)R * D + col] = (short)f2bf(fmaxf(acc[rt][ct][j] + bcol[ct], 0.f));
                    }
                }
            }
    } else if constexpr (MODE == 1) {
        __syncthreads();                        // smem reuse for cross-wave row sums
        float* ssb = (float*)smem;              // [2 wc][128 rows]
        #pragma unroll
        for (int rt = 0; rt < 4; ++rt)
            #pragma unroll
            for (int j = 0; j < 4; ++j) {
                float ss = 0.f;
                #pragma unroll
                for (int ct = 0; ct < 4; ++ct) {
                    float v = fmaxf(acc[rt][ct][j] + bcol[ct], 0.f);
                    acc[rt][ct][j] = v;
                    ss += v * v;
                }
                ss += __shfl_xor(ss, 1); ss += __shfl_xor(ss, 2);
                ss += __shfl_xor(ss, 4); ss += __shfl_xor(ss, 8);
                if (lrow == 0) ssb[wc * 128 + wr * 64 + rt * 16 + g * 4 + j] = ss;
            }
        __syncthreads();
        #pragma unroll
        for (int rt = 0; rt < 4; ++rt)
            #pragma unroll
            for (int j = 0; j < 4; ++j) {
                int r = wr * 64 + rt * 16 + g * 4 + j;
                int R = row0 + r;
                float tot = ssb[r] + ssb[128 + r];
                float inv = 1.f / fmaxf(sqrtf(tot), 1e-12f);
                if (R < nrows) {
                    #pragma unroll
                    for (int ct = 0; ct < 4; ++ct) {
                        int col = wc * 64 + ct * 16 + lrow;
                        float v = acc[rt][ct][j] * inv;
                        unsigned short hh = f2bf(v);
                        Oh[(size_t)R * D + col] = (short)hh;
                        Ol[(size_t)R * D + col] = (short)f2bf(v - bf2f(hh));
                    }
                }
            }
    } else {                                    // MODE 2: l2norm + predictor projection
        float2 wpsv[4], wpdv[4];
        #pragma unroll
        for (int ct = 0; ct < 4; ++ct) {
            int col = wc * 64 + ct * 16 + lrow;
            wpsv[ct] = *(const float2*)(Wpred + col * 2);
            wpdv[ct] = *(const float2*)(Wpred + (128 + col) * 2);
        }
        __syncthreads();
        float* pb = (float*)smem;               // [(wc*128 + r)*5 + q]
        #pragma unroll
        for (int rt = 0; rt < 4; ++rt)
            #pragma unroll
            for (int j = 0; j < 4; ++j) {
                float ss = 0.f, sa0 = 0.f, sa1 = 0.f, sb0 = 0.f, sb1 = 0.f;
                #pragma unroll
                for (int ct = 0; ct < 4; ++ct) {
                    float v = acc[rt][ct][j] + bcol[ct];     // no relu in layer-2 output
                    ss  += v * v;
                    sa0 = fmaf(v, wpsv[ct].x, sa0); sa1 = fmaf(v, wpsv[ct].y, sa1);
                    sb0 = fmaf(v, wpdv[ct].x, sb0); sb1 = fmaf(v, wpdv[ct].y, sb1);
                }
                #pragma unroll
                for (int msk = 1; msk < 16; msk <<= 1) {
                    ss  += __shfl_xor(ss, msk);
                    sa0 += __shfl_xor(sa0, msk); sa1 += __shfl_xor(sa1, msk);
                    sb0 += __shfl_xor(sb0, msk); sb1 += __shfl_xor(sb1, msk);
                }
                if (lrow == 0) {
                    int r = wr * 64 + rt * 16 + g * 4 + j;
                    float* q = pb + (wc * 128 + r) * 5;
                    q[0] = ss; q[1] = sa0; q[2] = sa1; q[3] = sb0; q[4] = sb1;
                }
            }
        __syncthreads();
        if (tid < 128) {
            int R = row0 + tid;
            if (R < nrows) {
                const float* q0 = pb + tid * 5;
                const float* q1 = pb + (128 + tid) * 5;
                float inv = 1.f / fmaxf(sqrtf(q0[0] + q1[0]), 1e-12f);
                ps[(size_t)R * 2 + 0] = inv * (q0[1] + q1[1]);
                ps[(size_t)R * 2 + 1] = inv * (q0[2] + q1[2]);
                pd[(size_t)R * 2 + 0] = inv * (q0[3] + q1[3]);
                pd[(size_t)R * 2 + 1] = inv * (q0[4] + q1[4]);
            }
        }
    }
}

// ---------------- segment-max over CSR, bf16 in / bf16 out ----------------
// One wave per node; each 32-lane half handles one in-edge, 4 feats (8B)/lane.
// Packed-u16 max valid: values are relu outputs (>=0) in bf16; empty segment -> 0.
__global__ __launch_bounds__(256) void k_aggmax(
    const unsigned short* __restrict__ m, const int* __restrict__ csr,
    const int* __restrict__ offs_end, const int* __restrict__ counts,
    unsigned short* __restrict__ aggh, int n)
{
    int gid  = blockIdx.x * blockDim.x + threadIdx.x;
    int node = gid >> 6;
    int lane = threadIdx.x & 63;
    if (node >= n) return;
    const int cnt   = counts[node];
    const int start = offs_end[node] - cnt;
    const int half  = lane >> 5;
    const unsigned short* mf = m + (lane & 31) * 4;
    uint2 a0 = make_uint2(0u, 0u), a1 = make_uint2(0u, 0u);
    int i = 0;
    for (; i + 4 <= cnt; i += 4) {                 // 4 rows in flight per wave
        int s0 = csr[start + i + half];
        int s1 = csr[start + i + 2 + half];
        uint2 v0 = *(const uint2*)(mf + (size_t)s0 * D);
        uint2 v1 = *(const uint2*)(mf + (size_t)s1 * D);
        a0.x = pmaxu16(a0.x, v0.x); a0.y = pmaxu16(a0.y, v0.y);
        a1.x = pmaxu16(a1.x, v1.x); a1.y = pmaxu16(a1.y, v1.y);
    }
    if (i + 2 <= cnt) {
        int s0 = csr[start + i + half];
        uint2 v0 = *(const uint2*)(mf + (size_t)s0 * D);
        a0.x = pmaxu16(a0.x, v0.x); a0.y = pmaxu16(a0.y, v0.y);
        i += 2;
    }
    if (i < cnt) {                                  // odd tail: both halves same row (idempotent)
        int s0 = csr[start + i];
        uint2 v0 = *(const uint2*)(mf + (size_t)s0 * D);
        a0.x = pmaxu16(a0.x, v0.x); a0.y = pmaxu16(a0.y, v0.y);
    }
    a0.x = pmaxu16(a0.x, a1.x); a0.y = pmaxu16(a0.y, a1.y);
    a0.x = pmaxu16(a0.x, (unsigned)__shfl_xor((int)a0.x, 32));
    a0.y = pmaxu16(a0.y, (unsigned)__shfl_xor((int)a0.y, 32));
    if (half == 0)
        *(uint2*)(aggh + (size_t)node * D + (lane & 31) * 4) = a0;
}

// ---------------- edge scores ----------------
__global__ void k_edge(const int* __restrict__ src, const int* __restrict__ dst,
                       const float* __restrict__ ps, const float* __restrict__ pd,
                       const float* __restrict__ bpred, float* __restrict__ out, int E)
{
    int e = blockIdx.x * blockDim.x + threadIdx.x;
    if (e >= E) return;
    int s = src[e], d = dst[e];
    const float2 a = *(const float2*)(ps + 2 * (size_t)s);
    const float2 b = *(const float2*)(pd + 2 * (size_t)d);
    float2 o;
    o.x = a.x + b.x + bpred[0];
    o.y = a.y + b.y + bpred[1];
    *(float2*)(out + 2 * (size_t)e) = o;
}

extern "C" void kernel_launch(void* const* d_in, const int* in_sizes, int n_in,
                              void* d_out, int out_size, void* d_ws, size_t ws_size,
                              hipStream_t stream) {
    const float* x     = (const float*)d_in[0];
    const int*   src   = (const int*)d_in[1];
    const int*   dst   = (const int*)d_in[2];
    const float* Wp1   = (const float*)d_in[3];
    const float* bp1   = (const float*)d_in[4];
    const float* Ws1   = (const float*)d_in[5];
    const float* Wn1   = (const float*)d_in[6];
    const float* b1    = (const float*)d_in[7];
    const float* Wp2   = (const float*)d_in[8];
    const float* bp2   = (const float*)d_in[9];
    const float* Ws2   = (const float*)d_in[10];
    const float* Wn2   = (const float*)d_in[11];
    const float* b2    = (const float*)d_in[12];
    const float* Wpred = (const float*)d_in[13];
    const float* bpred = (const float*)d_in[14];
    float* out = (float*)d_out;

    const int N  = in_sizes[0] / D;
    const int E  = in_sizes[1];
    const int NP = ((N + 127) / 128) * 128 + 128;   // padded rows (staging reads past tail)

    char* ws = (char*)d_ws;
    size_t o = 0;
    auto carve = [&](size_t bytes) { void* p = ws + o; o += (bytes + 255) & ~(size_t)255; return p; };
    short* xh    = (short*)carve((size_t)NP * D * 2);   // becomes h1h in-place
    short* xl    = (short*)carve((size_t)NP * D * 2);   // becomes h1l in-place
    short* aggh  = (short*)carve((size_t)NP * D * 2);
    short* mh    = (short*)carve((size_t)NP * D * 2);   // m1 / m2, bf16
    short* wth   = (short*)carve((size_t)6 * D * D * 2);
    short* wtl   = (short*)carve((size_t)6 * D * D * 2);
    float* ps    = (float*)carve((size_t)N * 2 * 4);
    float* pd    = (float*)carve((size_t)N * 2 * 4);
    int*   counts= (int*)carve((size_t)N * 4);
    int*   offs  = (int*)carve((size_t)N * 4);
    int*   bsum  = (int*)carve(4096);
    int*   csr   = (int*)carve((size_t)E * 4);
    (void)ws_size; (void)n_in; (void)out_size;

    hipMemsetAsync(counts, 0, (size_t)N * 4, stream);

    // prep: splits
    const int n4 = N * D / 4;
    k_split<<<(n4 + 255) / 256, 256, 0, stream>>>(x, xh, xl, n4);
    WArgs wa;
    const float* wsrc[6] = { Wp1, Ws1, Wn1, Wp2, Ws2, Wn2 };
    for (int i = 0; i < 6; ++i) {
        wa.s[i] = wsrc[i];
        wa.h[i] = wth + (size_t)i * D * D;
        wa.l[i] = wtl + (size_t)i * D * D;
    }
    k_wsplit<<<6, 256, 0, stream>>>(wa);

    const int B1 = (N + 1023) / 1024;
    const int EB = (E + 255) / 256;
    const int GB = (N + 127) / 128;

    // CSR by dst (offs becomes END offsets after scatter; aggmax uses offs - counts)
    k_count  <<<EB, 256, 0, stream>>>(dst, counts, E);
    k_scan1  <<<B1, 1024, 0, stream>>>(counts, offs, bsum, N);
    k_scan2  <<<1, 1024, 0, stream>>>(bsum, B1);
    k_scan3  <<<B1, 1024, 0, stream>>>(offs, bsum, N);
    k_scatter<<<EB, 256, 0, stream>>>(src, dst, offs, csr, E);

    short* Wp1h = wa.h[0]; short* Wp1l = wa.l[0];
    short* Ws1h = wa.h[1]; short* Ws1l = wa.l[1];
    short* Wn1h = wa.h[2]; short* Wn1l = wa.l[2];
    short* Wp2h = wa.h[3]; short* Wp2l = wa.l[3];
    short* Ws2h = wa.h[4]; short* Ws2l = wa.l[4];
    short* Wn2h = wa.h[5]; short* Wn2l = wa.l[5];

    // layer 1
    k_mgemm<false, 0><<<GB, 256, 0, stream>>>(xh, xl, nullptr, Wp1h, Wp1l, nullptr, nullptr,
                                              bp1, mh, nullptr, nullptr, nullptr, nullptr, nullptr, N);
    k_aggmax<<<(N + 3) / 4, 256, 0, stream>>>((const unsigned short*)mh, csr, offs, counts,
                                              (unsigned short*)aggh, N);
    // h1 written in-place over xh/xl (rows are block-local; all loads issued before epilogue)
    k_mgemm<true, 1><<<GB, 256, 0, stream>>>(xh, xl, aggh, Ws1h, Ws1l, Wn1h, Wn1l,
                                             b1, nullptr, xh, xl, nullptr, nullptr, nullptr, N);
    // layer 2
    k_mgemm<false, 0><<<GB, 256, 0, stream>>>(xh, xl, nullptr, Wp2h, Wp2l, nullptr, nullptr,
                                              bp2, mh, nullptr, nullptr, nullptr, nullptr, nullptr, N);
    k_aggmax<<<(N + 3) / 4, 256, 0, stream>>>((const unsigned short*)mh, csr, offs, counts,
                                              (unsigned short*)aggh, N);
    k_mgemm<true, 2><<<GB, 256, 0, stream>>>(xh, xl, aggh, Ws2h, Ws2l, Wn2h, Wn2l,
                                             b2, nullptr, nullptr, nullptr, Wpred, ps, pd, N);

    // edge scores
    k_edge<<<EB, 256, 0, stream>>>(src, dst, ps, pd, bpred, out, E);
}